// Round 5
// baseline (986.128 us; speedup 1.0000x reference)
//
#include <hip/hip_runtime.h>
#include <math.h>

#define NNODES 50000
#define NEDGES 800000
#define FIN    1433
#define KP1    1440   // FIN padded to multiple of 32
#define HDIM   256
#define NCLS   7
#define MPAD   50048  // NNODES padded to multiple of 128

typedef __attribute__((ext_vector_type(8))) short short8;
typedef __attribute__((ext_vector_type(4))) float f32x4;

__device__ __forceinline__ unsigned short f2bf(float f) {
    unsigned u = __builtin_bit_cast(unsigned, f);
    u += 0x7fffu + ((u >> 16) & 1u);          // round-to-nearest-even
    return (unsigned short)(u >> 16);
}

__device__ __forceinline__ float bf2f(unsigned short u) {
    unsigned v = ((unsigned)u) << 16;
    return __builtin_bit_cast(float, v);
}

// ---------------- CSR construction ----------------

__global__ void count_kernel(const int* __restrict__ col, int* __restrict__ cnt, int E) {
    int e = blockIdx.x * blockDim.x + threadIdx.x;
    if (e < E) atomicAdd(&cnt[col[e]], 1);
}

// scan + dinv fused
__global__ __launch_bounds__(1024) void scan_kernel(const int* __restrict__ cnt,
                                                    int* __restrict__ rp,
                                                    float* __restrict__ dinv,
                                                    int n, int total) {
    __shared__ int sums[1024];
    int t = threadIdx.x;
    int chunk = (n + 1023) >> 10;
    int start = t * chunk;
    int end = start + chunk; if (end > n) end = n;
    int local = 0;
    for (int j = start; j < end; ++j) local += cnt[j];
    sums[t] = local;
    __syncthreads();
    for (int off = 1; off < 1024; off <<= 1) {
        int v = (t >= off) ? sums[t - off] : 0;
        __syncthreads();
        sums[t] += v;
        __syncthreads();
    }
    int run = (t == 0) ? 0 : sums[t - 1];
    for (int j = start; j < end; ++j) {
        int c = cnt[j];
        rp[j] = run; run += c;
        dinv[j] = rsqrtf((float)(c + 1));
    }
    if (t == 0) rp[n] = total;
}

__global__ void fill_kernel(const int* __restrict__ row, const int* __restrict__ col,
                            const int* __restrict__ rp, int* __restrict__ cur,
                            int* __restrict__ csr, int E) {
    int e = blockIdx.x * blockDim.x + threadIdx.x;
    if (e < E) {
        int c = col[e];
        int pos = rp[c] + atomicAdd(&cur[c], 1);
        csr[pos] = row[e];
    }
}

// ---------------- weight transpose+cast: Wt[Nn][Kp] <- W[Kin][Nn] ----------------

__global__ void cast_wt_kernel(const float* __restrict__ W, unsigned short* __restrict__ Wt,
                               int Kin, int Kp, int Nn) {
    int idx = blockIdx.x * blockDim.x + threadIdx.x;
    if (idx >= Nn * Kp) return;
    int n = idx / Kp, k = idx % Kp;
    float f = (k < Kin) ? W[(size_t)k * Nn + n] : 0.f;
    Wt[idx] = f2bf(f);
}

// ---------------- layer-1 GEMM, barrier-free direct fragments ----------------
// C[NNODES,256] bf16 = X[N,FIN] f32 @ W1t[256,KP1]^T bf16.
// BM=64, BN=256, 256 thr = 4 waves; wave w -> col strip w*64, all 64 rows.
// A frag: lane reads 8 consecutive f32 of row m0+i*16+(lane&15) at k=k0+(lane>>4)*8,
// converts in regs. B frag: 16B load of w1t row wn+j*16+(lane&15). No LDS, no barriers.

__global__ __launch_bounds__(256) void gemm1_direct(const float* __restrict__ X,
                                                    const unsigned short* __restrict__ Bt,
                                                    unsigned short* __restrict__ C) {
    const int tid = threadIdx.x;
    const int wave = tid >> 6, lane = tid & 63;
    const int m0 = blockIdx.x * 64;
    const int wn = wave * 64;
    const int kq = lane >> 4;
    const int l16 = lane & 15;

    const float* xrow[4];
    #pragma unroll
    for (int i = 0; i < 4; ++i) {
        int r = m0 + i * 16 + l16;
        if (r >= NNODES) r = NNODES - 1;   // clamp (stay in-bounds; bad rows filtered at store)
        xrow[i] = X + (size_t)r * FIN + kq * 8;
    }
    const unsigned short* brow[4];
    #pragma unroll
    for (int j = 0; j < 4; ++j)
        brow[j] = Bt + (size_t)(wn + j * 16 + l16) * KP1 + kq * 8;

    f32x4 acc[4][4] = {};

    // full iterations: k0+kq*8+7 <= 1376+31 = 1407 < FIN, unguarded
    for (int k0 = 0; k0 < 1408; k0 += 32) {
        short8 af[4], bfr[4];
        #pragma unroll
        for (int i = 0; i < 4; ++i) {
            float f[8];
            #pragma unroll
            for (int j = 0; j < 8; ++j) f[j] = xrow[i][k0 + j];
            #pragma unroll
            for (int j = 0; j < 8; ++j) af[i][j] = (short)f2bf(f[j]);
        }
        #pragma unroll
        for (int j = 0; j < 4; ++j) bfr[j] = *(const short8*)(brow[j] + k0);
        #pragma unroll
        for (int i = 0; i < 4; ++i)
            #pragma unroll
            for (int j = 0; j < 4; ++j)
                acc[i][j] = __builtin_amdgcn_mfma_f32_16x16x32_bf16(af[i], bfr[j], acc[i][j], 0, 0, 0);
    }
    {   // tail k0 = 1408: guard k >= FIN (only kq==3 partially OOB); Bt is zero-padded
        const int k0 = 1408;
        const int kb = k0 + kq * 8;
        short8 af[4], bfr[4];
        #pragma unroll
        for (int i = 0; i < 4; ++i) {
            #pragma unroll
            for (int j = 0; j < 8; ++j) {
                float f = (kb + j < FIN) ? xrow[i][k0 + j] : 0.f;
                af[i][j] = (short)f2bf(f);
            }
        }
        #pragma unroll
        for (int j = 0; j < 4; ++j) bfr[j] = *(const short8*)(brow[j] + k0);
        #pragma unroll
        for (int i = 0; i < 4; ++i)
            #pragma unroll
            for (int j = 0; j < 4; ++j)
                acc[i][j] = __builtin_amdgcn_mfma_f32_16x16x32_bf16(af[i], bfr[j], acc[i][j], 0, 0, 0);
    }

    // C/D layout: col = lane&15, row = (lane>>4)*4 + reg
    #pragma unroll
    for (int i = 0; i < 4; ++i) {
        int gm_base = m0 + i * 16 + (lane >> 4) * 4;
        #pragma unroll
        for (int r = 0; r < 4; ++r) {
            int gm = gm_base + r;
            if (gm < NNODES) {
                #pragma unroll
                for (int j = 0; j < 4; ++j) {
                    int gn = wn + j * 16 + l16;
                    C[(size_t)gm * HDIM + gn] = f2bf(acc[i][j][r]);
                }
            }
        }
    }
}

// ---------------- layer-2 GEMM, barrier-free direct fragments (bf16 A) ----------------
// C[NNODES,256] bf16 = A[MPAD,256] bf16 @ W2t[256,256]^T bf16. Same structure, K=256.

__global__ __launch_bounds__(256) void gemm2_direct(const unsigned short* __restrict__ A,
                                                    const unsigned short* __restrict__ Bt,
                                                    unsigned short* __restrict__ C) {
    const int tid = threadIdx.x;
    const int wave = tid >> 6, lane = tid & 63;
    const int m0 = blockIdx.x * 64;
    const int wn = wave * 64;
    const int kq = lane >> 4;
    const int l16 = lane & 15;

    const unsigned short* arow[4];
    #pragma unroll
    for (int i = 0; i < 4; ++i)
        arow[i] = A + (size_t)(m0 + i * 16 + l16) * HDIM + kq * 8;  // pad rows exist (poison, finite)
    const unsigned short* brow[4];
    #pragma unroll
    for (int j = 0; j < 4; ++j)
        brow[j] = Bt + (size_t)(wn + j * 16 + l16) * HDIM + kq * 8;

    f32x4 acc[4][4] = {};
    #pragma unroll
    for (int k0 = 0; k0 < HDIM; k0 += 32) {
        short8 af[4], bfr[4];
        #pragma unroll
        for (int i = 0; i < 4; ++i) af[i]  = *(const short8*)(arow[i] + k0);
        #pragma unroll
        for (int j = 0; j < 4; ++j) bfr[j] = *(const short8*)(brow[j] + k0);
        #pragma unroll
        for (int i = 0; i < 4; ++i)
            #pragma unroll
            for (int j = 0; j < 4; ++j)
                acc[i][j] = __builtin_amdgcn_mfma_f32_16x16x32_bf16(af[i], bfr[j], acc[i][j], 0, 0, 0);
    }

    #pragma unroll
    for (int i = 0; i < 4; ++i) {
        int gm_base = m0 + i * 16 + (lane >> 4) * 4;
        #pragma unroll
        for (int r = 0; r < 4; ++r) {
            int gm = gm_base + r;
            if (gm < NNODES) {
                #pragma unroll
                for (int j = 0; j < 4; ++j) {
                    int gn = wn + j * 16 + l16;
                    C[(size_t)gm * HDIM + gn] = f2bf(acc[i][j][r]);
                }
            }
        }
    }
}

// ---------------- aggregation layer 1 (bf16 in/out, f32 accumulate) ----------------

__global__ __launch_bounds__(256) void agg_kernel(const ushort4* __restrict__ h,
                                                  ushort4* __restrict__ out,
                                                  const float* __restrict__ dinv,
                                                  const int* __restrict__ rp,
                                                  const int* __restrict__ csr,
                                                  const float* __restrict__ bias,
                                                  int n) {
    int node = blockIdx.x * 4 + (threadIdx.x >> 6);
    int lane = threadIdx.x & 63;
    if (node >= n) return;
    float di = dinv[node];
    float sw = di * di;
    ushort4 hv = h[node * 64 + lane];
    float ax = sw * bf2f(hv.x), ay = sw * bf2f(hv.y);
    float az = sw * bf2f(hv.z), aw = sw * bf2f(hv.w);
    int p0 = rp[node], p1 = rp[node + 1];
    for (int p = p0; p < p1; ++p) {
        int s = csr[p];
        float wgt = dinv[s] * di;
        ushort4 t = h[s * 64 + lane];
        ax += wgt * bf2f(t.x); ay += wgt * bf2f(t.y);
        az += wgt * bf2f(t.z); aw += wgt * bf2f(t.w);
    }
    float4 b = ((const float4*)bias)[lane];
    ax = fmaxf(ax + b.x, 0.f); ay = fmaxf(ay + b.y, 0.f);
    az = fmaxf(az + b.z, 0.f); aw = fmaxf(aw + b.w, 0.f);
    out[node * 64 + lane] = make_ushort4(f2bf(ax), f2bf(ay), f2bf(az), f2bf(aw));
}

// ---------------- aggregation layer 2 fused with mm3: h3[N,7] ----------------

__global__ __launch_bounds__(256) void agg2_mm3_kernel(const ushort4* __restrict__ h,
                                                       float* __restrict__ h3,
                                                       const float* __restrict__ dinv,
                                                       const int* __restrict__ rp,
                                                       const int* __restrict__ csr,
                                                       const float* __restrict__ bias,
                                                       const float* __restrict__ W3,
                                                       int n) {
    __shared__ __align__(16) float Ws[NCLS * HDIM];   // Ws[c*256 + k] = W3[k*7 + c]
    int tid = threadIdx.x;
    for (int i = tid; i < NCLS * HDIM; i += 256)
        Ws[i] = W3[(i & 255) * NCLS + (i >> 8)];
    __syncthreads();

    int node = blockIdx.x * 4 + (tid >> 6);
    int lane = tid & 63;
    if (node >= n) return;
    float di = dinv[node];
    float sw = di * di;
    ushort4 hv = h[node * 64 + lane];
    float ax = sw * bf2f(hv.x), ay = sw * bf2f(hv.y);
    float az = sw * bf2f(hv.z), aw = sw * bf2f(hv.w);
    int p0 = rp[node], p1 = rp[node + 1];
    for (int p = p0; p < p1; ++p) {
        int s = csr[p];
        float wgt = dinv[s] * di;
        ushort4 t = h[s * 64 + lane];
        ax += wgt * bf2f(t.x); ay += wgt * bf2f(t.y);
        az += wgt * bf2f(t.z); aw += wgt * bf2f(t.w);
    }
    float4 b = ((const float4*)bias)[lane];
    ax = fmaxf(ax + b.x, 0.f); ay = fmaxf(ay + b.y, 0.f);
    az = fmaxf(az + b.z, 0.f); aw = fmaxf(aw + b.w, 0.f);

    float p7[NCLS];
    #pragma unroll
    for (int c = 0; c < NCLS; ++c) {
        float4 w4 = *(const float4*)&Ws[c * HDIM + 4 * lane];
        p7[c] = ax * w4.x + ay * w4.y + az * w4.z + aw * w4.w;
    }
    #pragma unroll
    for (int c = 0; c < NCLS; ++c)
        for (int off = 32; off > 0; off >>= 1) p7[c] += __shfl_down(p7[c], off);
    if (lane == 0) {
        #pragma unroll
        for (int c = 0; c < NCLS; ++c) h3[node * NCLS + c] = p7[c];
    }
}

// ---------------- layer-3 aggregation + bias + log_softmax ----------------

__global__ void final_kernel(const float* __restrict__ h3, const float* __restrict__ dinv,
                             const int* __restrict__ rp, const int* __restrict__ csr,
                             const float* __restrict__ b3, float* __restrict__ out, int n) {
    int i = blockIdx.x * blockDim.x + threadIdx.x;
    if (i >= n) return;
    float di = dinv[i];
    float sw = di * di;
    float acc[NCLS];
    #pragma unroll
    for (int c = 0; c < NCLS; ++c) acc[c] = sw * h3[i * NCLS + c];
    int p0 = rp[i], p1 = rp[i + 1];
    for (int p = p0; p < p1; ++p) {
        int s = csr[p];
        float wgt = dinv[s] * di;
        #pragma unroll
        for (int c = 0; c < NCLS; ++c) acc[c] += wgt * h3[s * NCLS + c];
    }
    float mx = -1e30f;
    #pragma unroll
    for (int c = 0; c < NCLS; ++c) { acc[c] += b3[c]; mx = fmaxf(mx, acc[c]); }
    float sum = 0.f;
    #pragma unroll
    for (int c = 0; c < NCLS; ++c) sum += expf(acc[c] - mx);
    float lse = mx + logf(sum);
    #pragma unroll
    for (int c = 0; c < NCLS; ++c) out[i * NCLS + c] = acc[c] - lse;
}

// ---------------- launch ----------------

extern "C" void kernel_launch(void* const* d_in, const int* in_sizes, int n_in,
                              void* d_out, int out_size, void* d_ws, size_t ws_size,
                              hipStream_t stream) {
    const float* x  = (const float*)d_in[0];
    const int*   ei = (const int*)d_in[1];
    const float* W1 = (const float*)d_in[2];
    const float* b1 = (const float*)d_in[3];
    const float* W2 = (const float*)d_in[4];
    const float* b2 = (const float*)d_in[5];
    const float* W3 = (const float*)d_in[6];
    const float* b3 = (const float*)d_in[7];
    float* out = (float*)d_out;
    const int* row = ei;
    const int* col = ei + NEDGES;

    char* w = (char*)d_ws;
    auto alloc = [&](size_t b) { void* p = (void*)w; w += (b + 255) & ~(size_t)255; return p; };
    int*   cnt  = (int*)alloc(NNODES * 4);
    int*   cur  = (int*)alloc(NNODES * 4);
    int*   rp   = (int*)alloc((NNODES + 1) * 4);
    float* dinv = (float*)alloc(NNODES * 4);
    int*   csr  = (int*)alloc((size_t)NEDGES * 4);
    unsigned short* w1t  = (unsigned short*)alloc((size_t)HDIM * KP1 * 2);
    unsigned short* w2t  = (unsigned short*)alloc((size_t)HDIM * HDIM * 2);
    unsigned short* h_bf = (unsigned short*)alloc((size_t)MPAD * HDIM * 2);
    unsigned short* a_bf = (unsigned short*)alloc((size_t)MPAD * HDIM * 2);
    float* h3 = (float*)alloc((size_t)NNODES * NCLS * 4);
    // pad rows of h_bf/a_bf hold finite poison; never stored (gm<NNODES) nor gathered
    // (CSR indices < NNODES), only fed into MFMA rows that are discarded.

    hipMemsetAsync(cnt, 0, NNODES * 4, stream);
    hipMemsetAsync(cur, 0, NNODES * 4, stream);
    count_kernel<<<(NEDGES + 255) / 256, 256, 0, stream>>>(col, cnt, NEDGES);
    scan_kernel<<<1, 1024, 0, stream>>>(cnt, rp, dinv, NNODES, NEDGES);
    fill_kernel<<<(NEDGES + 255) / 256, 256, 0, stream>>>(row, col, rp, cur, csr, NEDGES);

    cast_wt_kernel<<<(HDIM * KP1 + 255) / 256, 256, 0, stream>>>(W1, w1t, FIN, KP1, HDIM);
    cast_wt_kernel<<<(HDIM * HDIM + 255) / 256, 256, 0, stream>>>(W2, w2t, HDIM, HDIM, HDIM);

    gemm1_direct<<<MPAD / 64, 256, 0, stream>>>(x, w1t, h_bf);
    agg_kernel<<<(NNODES + 3) / 4, 256, 0, stream>>>((const ushort4*)h_bf, (ushort4*)a_bf,
                                                     dinv, rp, csr, b1, NNODES);
    gemm2_direct<<<MPAD / 64, 256, 0, stream>>>(a_bf, w2t, h_bf);
    agg2_mm3_kernel<<<(NNODES + 3) / 4, 256, 0, stream>>>((const ushort4*)h_bf, h3,
                                                          dinv, rp, csr, b2, W3, NNODES);
    final_kernel<<<(NNODES + 255) / 256, 256, 0, stream>>>(h3, dinv, rp, csr, b3, out, NNODES);
}

// Round 6
// 791.653 us; speedup vs baseline: 1.2457x; 1.2457x over previous
//
#include <hip/hip_runtime.h>
#include <math.h>
#include <type_traits>

#define NNODES 50000
#define NEDGES 800000
#define FIN    1433
#define KP1    1472   // FIN padded to multiple of 64
#define HDIM   256
#define NCLS   7
#define MPAD   50048  // NNODES padded to multiple of 64

typedef __attribute__((ext_vector_type(8))) short short8;
typedef __attribute__((ext_vector_type(4))) float f32x4;

__device__ __forceinline__ unsigned short f2bf(float f) {
    unsigned u = __builtin_bit_cast(unsigned, f);
    u += 0x7fffu + ((u >> 16) & 1u);          // round-to-nearest-even
    return (unsigned short)(u >> 16);
}

__device__ __forceinline__ float bf2f(unsigned short u) {
    unsigned v = ((unsigned)u) << 16;
    return __builtin_bit_cast(float, v);
}

__device__ __forceinline__ void gl2lds16(const void* g, void* l) {
    __builtin_amdgcn_global_load_lds(
        (const __attribute__((address_space(1))) unsigned int*)g,
        (__attribute__((address_space(3))) unsigned int*)l, 16, 0, 0);
}

// ---------------- CSR construction ----------------

__global__ void count_kernel(const int* __restrict__ col, int* __restrict__ cnt, int E) {
    int e = blockIdx.x * blockDim.x + threadIdx.x;
    if (e < E) atomicAdd(&cnt[col[e]], 1);
}

__global__ __launch_bounds__(1024) void scan_kernel(const int* __restrict__ cnt,
                                                    int* __restrict__ rp,
                                                    float* __restrict__ dinv,
                                                    int n, int total) {
    __shared__ int sums[1024];
    int t = threadIdx.x;
    int chunk = (n + 1023) >> 10;
    int start = t * chunk;
    int end = start + chunk; if (end > n) end = n;
    int local = 0;
    for (int j = start; j < end; ++j) local += cnt[j];
    sums[t] = local;
    __syncthreads();
    for (int off = 1; off < 1024; off <<= 1) {
        int v = (t >= off) ? sums[t - off] : 0;
        __syncthreads();
        sums[t] += v;
        __syncthreads();
    }
    int run = (t == 0) ? 0 : sums[t - 1];
    for (int j = start; j < end; ++j) {
        int c = cnt[j];
        rp[j] = run; run += c;
        dinv[j] = rsqrtf((float)(c + 1));
    }
    if (t == 0) rp[n] = total;
}

// fill + per-edge weight precompute (dinv ready: scan runs before fill)
__global__ void fill_kernel(const int* __restrict__ row, const int* __restrict__ col,
                            const int* __restrict__ rp, int* __restrict__ cur,
                            int* __restrict__ csr, float* __restrict__ wcsr,
                            const float* __restrict__ dinv, int E) {
    int e = blockIdx.x * blockDim.x + threadIdx.x;
    if (e < E) {
        int c = col[e], r = row[e];
        int pos = rp[c] + atomicAdd(&cur[c], 1);
        csr[pos] = r;
        wcsr[pos] = dinv[r] * dinv[c];
    }
}

// ---------------- weight transpose+cast: Wt[Nn][Kp] <- W[Kin][Nn] ----------------

__global__ void cast_wt_kernel(const float* __restrict__ W, unsigned short* __restrict__ Wt,
                               int Kin, int Kp, int Nn) {
    int idx = blockIdx.x * blockDim.x + threadIdx.x;
    if (idx >= Nn * Kp) return;
    int n = idx / Kp, k = idx % Kp;
    float f = (k < Kin) ? W[(size_t)k * Nn + n] : 0.f;
    Wt[idx] = f2bf(f);
}

// ---------------- layer-1 GEMM: fused cast, coalesced staging ----------------
// C[NNODES,256] bf16 = X[N,FIN] f32 @ W1t[256,KP1]^T bf16. BM=64, BN=256, BK=64.
// A: per instr one wave reads 64 consecutive f32 of one row (coalesced 256 B), cvt in regs,
// ds_write_b16 into XOR-swizzled chunk layout (2 lanes/bank = free).
// B: global_load_lds width-16; swizzle folded into per-lane GLOBAL address (LDS side linear).
// LDS chunk (r, ccg) of 8 bf16 stored at r*64 + (ccg ^ (r&7))*8.

__global__ __launch_bounds__(256) void gemm1_fused(const float* __restrict__ X,
                                                   const unsigned short* __restrict__ Bt,
                                                   unsigned short* __restrict__ C) {
    __shared__ __align__(16) unsigned short As[64 * 64];    // 8 KB
    __shared__ __align__(16) unsigned short Bs[256 * 64];   // 32 KB
    const int tid = threadIdx.x;
    const int wave = tid >> 6, lane = tid & 63;
    const int m0 = blockIdx.x * 64;
    const int wn = wave * 64;
    const int kq = lane >> 4, l16 = lane & 15, l8 = lane & 7, lh = lane >> 3;

    int rowbase[16];
    #pragma unroll
    for (int i = 0; i < 16; ++i) {
        int r = m0 + i * 4 + wave;             // wave w stages rows {i*4+w}
        if (r >= NNODES) r = NNODES - 1;       // clamp: stay in-bounds, filtered at store
        rowbase[i] = r * FIN;
    }
    // LDS write index: row = i*4+wave -> row&7 = wave + 4*(i&1)
    const int aw0 = wave * 64 + ((lh ^ wave) * 8) + l8;
    const int aw1 = wave * 64 + ((lh ^ (wave + 4)) * 8) + l8;

    int bo[8];
    #pragma unroll
    for (int i = 0; i < 8; ++i) {
        int c = i * 256 + tid;                 // LDS chunk = linear c
        int n = c >> 3, ccg = (c & 7) ^ (n & 7);
        bo[i] = n * KP1 + ccg * 8;             // permuted global chunk
    }

    // fragment offsets: m = i*16+l16 -> m&7 = l16&7 (i*16 ≡ 0 mod 8); same for n
    int aoffb[2], boffb[2];
    #pragma unroll
    for (int ks = 0; ks < 2; ++ks) {
        int swz = ((ks * 4 + kq) ^ (l16 & 7)) * 8;
        aoffb[ks] = l16 * 64 + swz;
        boffb[ks] = (wn + l16) * 64 + swz;
    }

    f32x4 acc[4][4] = {};

    auto iter = [&](int k0, auto tailc) {
        constexpr bool TAIL = decltype(tailc)::value;
        const int k = k0 + lane;
        float fv[16];
        #pragma unroll
        for (int i = 0; i < 16; ++i)
            fv[i] = (!TAIL || k < FIN) ? X[rowbase[i] + k] : 0.f;   // value moot past FIN (Bt pad=0)
        #pragma unroll
        for (int i = 0; i < 8; ++i)
            gl2lds16(Bt + bo[i] + k0, &Bs[(i * 256 + tid) * 8]);
        #pragma unroll
        for (int i = 0; i < 16; ++i)
            As[i * 256 + ((i & 1) ? aw1 : aw0)] = f2bf(fv[i]);
        __syncthreads();
        #pragma unroll
        for (int ks = 0; ks < 2; ++ks) {
            short8 af[4], bg[4];
            #pragma unroll
            for (int i = 0; i < 4; ++i) af[i] = *(const short8*)&As[i * 1024 + aoffb[ks]];
            #pragma unroll
            for (int j = 0; j < 4; ++j) bg[j] = *(const short8*)&Bs[j * 1024 + boffb[ks]];
            #pragma unroll
            for (int i = 0; i < 4; ++i)
                #pragma unroll
                for (int j = 0; j < 4; ++j)
                    acc[i][j] = __builtin_amdgcn_mfma_f32_16x16x32_bf16(af[i], bg[j], acc[i][j], 0, 0, 0);
        }
        __syncthreads();
    };

    for (int k0 = 0; k0 < KP1 - 64; k0 += 64)
        iter(k0, std::integral_constant<bool, false>{});
    iter(KP1 - 64, std::integral_constant<bool, true>{});

    // C/D layout: col = lane&15, row = (lane>>4)*4 + reg
    #pragma unroll
    for (int i = 0; i < 4; ++i) {
        int gm_base = m0 + i * 16 + (lane >> 4) * 4;
        #pragma unroll
        for (int r = 0; r < 4; ++r) {
            int gm = gm_base + r;
            if (gm < NNODES) {
                #pragma unroll
                for (int j = 0; j < 4; ++j) {
                    int gn = wn + j * 16 + l16;
                    C[(size_t)gm * HDIM + gn] = f2bf(acc[i][j][r]);
                }
            }
        }
    }
}

// ---------------- layer-2 GEMM: bf16 A, all global_load_lds, BM=64 BN=256 BK=64 ----------

__global__ __launch_bounds__(256) void gemm2_lds(const unsigned short* __restrict__ A,
                                                 const unsigned short* __restrict__ Bt,
                                                 unsigned short* __restrict__ C) {
    __shared__ __align__(16) unsigned short As[64 * 64];
    __shared__ __align__(16) unsigned short Bs[256 * 64];
    const int tid = threadIdx.x;
    const int wave = tid >> 6, lane = tid & 63;
    const int m0 = blockIdx.x * 64;
    const int wn = wave * 64;
    const int kq = lane >> 4, l16 = lane & 15;

    int ao[2];
    #pragma unroll
    for (int i = 0; i < 2; ++i) {
        int c = i * 256 + tid;
        int m = c >> 3, ccg = (c & 7) ^ (m & 7);
        ao[i] = (m0 + m) * HDIM + ccg * 8;     // pad rows: finite poison, discarded at store
    }
    int bo[8];
    #pragma unroll
    for (int i = 0; i < 8; ++i) {
        int c = i * 256 + tid;
        int n = c >> 3, ccg = (c & 7) ^ (n & 7);
        bo[i] = n * HDIM + ccg * 8;
    }
    int aoffb[2], boffb[2];
    #pragma unroll
    for (int ks = 0; ks < 2; ++ks) {
        int swz = ((ks * 4 + kq) ^ (l16 & 7)) * 8;
        aoffb[ks] = l16 * 64 + swz;
        boffb[ks] = (wn + l16) * 64 + swz;
    }

    f32x4 acc[4][4] = {};
    #pragma unroll
    for (int k0 = 0; k0 < HDIM; k0 += 64) {
        #pragma unroll
        for (int i = 0; i < 2; ++i) gl2lds16(A + ao[i] + k0, &As[(i * 256 + tid) * 8]);
        #pragma unroll
        for (int i = 0; i < 8; ++i) gl2lds16(Bt + bo[i] + k0, &Bs[(i * 256 + tid) * 8]);
        __syncthreads();
        #pragma unroll
        for (int ks = 0; ks < 2; ++ks) {
            short8 af[4], bg[4];
            #pragma unroll
            for (int i = 0; i < 4; ++i) af[i] = *(const short8*)&As[i * 1024 + aoffb[ks]];
            #pragma unroll
            for (int j = 0; j < 4; ++j) bg[j] = *(const short8*)&Bs[j * 1024 + boffb[ks]];
            #pragma unroll
            for (int i = 0; i < 4; ++i)
                #pragma unroll
                for (int j = 0; j < 4; ++j)
                    acc[i][j] = __builtin_amdgcn_mfma_f32_16x16x32_bf16(af[i], bg[j], acc[i][j], 0, 0, 0);
        }
        __syncthreads();
    }

    #pragma unroll
    for (int i = 0; i < 4; ++i) {
        int gm_base = m0 + i * 16 + (lane >> 4) * 4;
        #pragma unroll
        for (int r = 0; r < 4; ++r) {
            int gm = gm_base + r;
            if (gm < NNODES) {
                #pragma unroll
                for (int j = 0; j < 4; ++j) {
                    int gn = wn + j * 16 + l16;
                    C[(size_t)gm * HDIM + gn] = f2bf(acc[i][j][r]);
                }
            }
        }
    }
}

// ---------------- aggregation layer 1 (bf16 in/out, precomputed weights, unroll-4) ---------

__global__ __launch_bounds__(256) void agg_kernel(const ushort4* __restrict__ h,
                                                  ushort4* __restrict__ out,
                                                  const float* __restrict__ dinv,
                                                  const int* __restrict__ rp,
                                                  const int* __restrict__ csr,
                                                  const float* __restrict__ wcsr,
                                                  const float* __restrict__ bias,
                                                  int n) {
    int node = blockIdx.x * 4 + (threadIdx.x >> 6);
    int lane = threadIdx.x & 63;
    if (node >= n) return;
    float di = dinv[node];
    float sw = di * di;
    ushort4 hv = h[node * 64 + lane];
    float ax = sw * bf2f(hv.x), ay = sw * bf2f(hv.y);
    float az = sw * bf2f(hv.z), aw = sw * bf2f(hv.w);
    int p = rp[node], p1 = rp[node + 1];
    for (; p + 4 <= p1; p += 4) {
        int s0 = csr[p], s1 = csr[p + 1], s2 = csr[p + 2], s3 = csr[p + 3];
        float w0 = wcsr[p], w1 = wcsr[p + 1], w2 = wcsr[p + 2], w3 = wcsr[p + 3];
        ushort4 t0 = h[s0 * 64 + lane], t1 = h[s1 * 64 + lane];
        ushort4 t2 = h[s2 * 64 + lane], t3 = h[s3 * 64 + lane];
        ax += w0 * bf2f(t0.x); ay += w0 * bf2f(t0.y); az += w0 * bf2f(t0.z); aw += w0 * bf2f(t0.w);
        ax += w1 * bf2f(t1.x); ay += w1 * bf2f(t1.y); az += w1 * bf2f(t1.z); aw += w1 * bf2f(t1.w);
        ax += w2 * bf2f(t2.x); ay += w2 * bf2f(t2.y); az += w2 * bf2f(t2.z); aw += w2 * bf2f(t2.w);
        ax += w3 * bf2f(t3.x); ay += w3 * bf2f(t3.y); az += w3 * bf2f(t3.z); aw += w3 * bf2f(t3.w);
    }
    for (; p < p1; ++p) {
        int s = csr[p];
        float wg = wcsr[p];
        ushort4 t = h[s * 64 + lane];
        ax += wg * bf2f(t.x); ay += wg * bf2f(t.y); az += wg * bf2f(t.z); aw += wg * bf2f(t.w);
    }
    float4 b = ((const float4*)bias)[lane];
    ax = fmaxf(ax + b.x, 0.f); ay = fmaxf(ay + b.y, 0.f);
    az = fmaxf(az + b.z, 0.f); aw = fmaxf(aw + b.w, 0.f);
    out[node * 64 + lane] = make_ushort4(f2bf(ax), f2bf(ay), f2bf(az), f2bf(aw));
}

// ---------------- aggregation layer 2 fused with mm3: h3[N,7] ----------------

__global__ __launch_bounds__(256) void agg2_mm3_kernel(const ushort4* __restrict__ h,
                                                       float* __restrict__ h3,
                                                       const float* __restrict__ dinv,
                                                       const int* __restrict__ rp,
                                                       const int* __restrict__ csr,
                                                       const float* __restrict__ wcsr,
                                                       const float* __restrict__ bias,
                                                       const float* __restrict__ W3,
                                                       int n) {
    __shared__ __align__(16) float Ws[NCLS * HDIM];   // Ws[c*256 + k] = W3[k*7 + c]
    int tid = threadIdx.x;
    for (int i = tid; i < NCLS * HDIM; i += 256)
        Ws[i] = W3[(i & 255) * NCLS + (i >> 8)];
    __syncthreads();

    int node = blockIdx.x * 4 + (tid >> 6);
    int lane = tid & 63;
    if (node >= n) return;
    float di = dinv[node];
    float sw = di * di;
    ushort4 hv = h[node * 64 + lane];
    float ax = sw * bf2f(hv.x), ay = sw * bf2f(hv.y);
    float az = sw * bf2f(hv.z), aw = sw * bf2f(hv.w);
    int p = rp[node], p1 = rp[node + 1];
    for (; p + 4 <= p1; p += 4) {
        int s0 = csr[p], s1 = csr[p + 1], s2 = csr[p + 2], s3 = csr[p + 3];
        float w0 = wcsr[p], w1 = wcsr[p + 1], w2 = wcsr[p + 2], w3 = wcsr[p + 3];
        ushort4 t0 = h[s0 * 64 + lane], t1 = h[s1 * 64 + lane];
        ushort4 t2 = h[s2 * 64 + lane], t3 = h[s3 * 64 + lane];
        ax += w0 * bf2f(t0.x); ay += w0 * bf2f(t0.y); az += w0 * bf2f(t0.z); aw += w0 * bf2f(t0.w);
        ax += w1 * bf2f(t1.x); ay += w1 * bf2f(t1.y); az += w1 * bf2f(t1.z); aw += w1 * bf2f(t1.w);
        ax += w2 * bf2f(t2.x); ay += w2 * bf2f(t2.y); az += w2 * bf2f(t2.z); aw += w2 * bf2f(t2.w);
        ax += w3 * bf2f(t3.x); ay += w3 * bf2f(t3.y); az += w3 * bf2f(t3.z); aw += w3 * bf2f(t3.w);
    }
    for (; p < p1; ++p) {
        int s = csr[p];
        float wg = wcsr[p];
        ushort4 t = h[s * 64 + lane];
        ax += wg * bf2f(t.x); ay += wg * bf2f(t.y); az += wg * bf2f(t.z); aw += wg * bf2f(t.w);
    }
    float4 b = ((const float4*)bias)[lane];
    ax = fmaxf(ax + b.x, 0.f); ay = fmaxf(ay + b.y, 0.f);
    az = fmaxf(az + b.z, 0.f); aw = fmaxf(aw + b.w, 0.f);

    float p7[NCLS];
    #pragma unroll
    for (int c = 0; c < NCLS; ++c) {
        float4 w4 = *(const float4*)&Ws[c * HDIM + 4 * lane];
        p7[c] = ax * w4.x + ay * w4.y + az * w4.z + aw * w4.w;
    }
    #pragma unroll
    for (int c = 0; c < NCLS; ++c)
        for (int off = 32; off > 0; off >>= 1) p7[c] += __shfl_down(p7[c], off);
    if (lane == 0) {
        #pragma unroll
        for (int c = 0; c < NCLS; ++c) h3[node * NCLS + c] = p7[c];
    }
}

// ---------------- layer-3 aggregation + bias + log_softmax ----------------

__global__ void final_kernel(const float* __restrict__ h3, const float* __restrict__ dinv,
                             const int* __restrict__ rp, const int* __restrict__ csr,
                             const float* __restrict__ wcsr,
                             const float* __restrict__ b3, float* __restrict__ out, int n) {
    int i = blockIdx.x * blockDim.x + threadIdx.x;
    if (i >= n) return;
    float di = dinv[i];
    float sw = di * di;
    float acc[NCLS];
    #pragma unroll
    for (int c = 0; c < NCLS; ++c) acc[c] = sw * h3[i * NCLS + c];
    int p = rp[i], p1 = rp[i + 1];
    for (; p + 2 <= p1; p += 2) {
        int s0 = csr[p], s1 = csr[p + 1];
        float w0 = wcsr[p], w1 = wcsr[p + 1];
        #pragma unroll
        for (int c = 0; c < NCLS; ++c) acc[c] += w0 * h3[s0 * NCLS + c] + w1 * h3[s1 * NCLS + c];
    }
    for (; p < p1; ++p) {
        int s = csr[p];
        float wg = wcsr[p];
        #pragma unroll
        for (int c = 0; c < NCLS; ++c) acc[c] += wg * h3[s * NCLS + c];
    }
    float mx = -1e30f;
    #pragma unroll
    for (int c = 0; c < NCLS; ++c) { acc[c] += b3[c]; mx = fmaxf(mx, acc[c]); }
    float sum = 0.f;
    #pragma unroll
    for (int c = 0; c < NCLS; ++c) sum += expf(acc[c] - mx);
    float lse = mx + logf(sum);
    #pragma unroll
    for (int c = 0; c < NCLS; ++c) out[i * NCLS + c] = acc[c] - lse;
}

// ---------------- launch ----------------

extern "C" void kernel_launch(void* const* d_in, const int* in_sizes, int n_in,
                              void* d_out, int out_size, void* d_ws, size_t ws_size,
                              hipStream_t stream) {
    const float* x  = (const float*)d_in[0];
    const int*   ei = (const int*)d_in[1];
    const float* W1 = (const float*)d_in[2];
    const float* b1 = (const float*)d_in[3];
    const float* W2 = (const float*)d_in[4];
    const float* b2 = (const float*)d_in[5];
    const float* W3 = (const float*)d_in[6];
    const float* b3 = (const float*)d_in[7];
    float* out = (float*)d_out;
    const int* row = ei;
    const int* col = ei + NEDGES;

    char* w = (char*)d_ws;
    auto alloc = [&](size_t b) { void* p = (void*)w; w += (b + 255) & ~(size_t)255; return p; };
    int*   cnt  = (int*)alloc(NNODES * 4);
    int*   cur  = (int*)alloc(NNODES * 4);
    int*   rp   = (int*)alloc((NNODES + 1) * 4);
    float* dinv = (float*)alloc(NNODES * 4);
    int*   csr  = (int*)alloc((size_t)NEDGES * 4);
    float* wcsr = (float*)alloc((size_t)NEDGES * 4);
    unsigned short* w1t  = (unsigned short*)alloc((size_t)HDIM * KP1 * 2);
    unsigned short* w2t  = (unsigned short*)alloc((size_t)HDIM * HDIM * 2);
    unsigned short* h_bf = (unsigned short*)alloc((size_t)MPAD * HDIM * 2);
    unsigned short* a_bf = (unsigned short*)alloc((size_t)MPAD * HDIM * 2);
    float* h3 = (float*)alloc((size_t)NNODES * NCLS * 4);

    hipMemsetAsync(cnt, 0, NNODES * 4, stream);
    hipMemsetAsync(cur, 0, NNODES * 4, stream);
    count_kernel<<<(NEDGES + 255) / 256, 256, 0, stream>>>(col, cnt, NEDGES);
    scan_kernel<<<1, 1024, 0, stream>>>(cnt, rp, dinv, NNODES, NEDGES);
    fill_kernel<<<(NEDGES + 255) / 256, 256, 0, stream>>>(row, col, rp, cur, csr, wcsr, dinv, NEDGES);

    cast_wt_kernel<<<(HDIM * KP1 + 255) / 256, 256, 0, stream>>>(W1, w1t, FIN, KP1, HDIM);
    cast_wt_kernel<<<(HDIM * HDIM + 255) / 256, 256, 0, stream>>>(W2, w2t, HDIM, HDIM, HDIM);

    gemm1_fused<<<MPAD / 64, 256, 0, stream>>>(x, w1t, h_bf);
    agg_kernel<<<(NNODES + 3) / 4, 256, 0, stream>>>((const ushort4*)h_bf, (ushort4*)a_bf,
                                                     dinv, rp, csr, wcsr, b1, NNODES);
    gemm2_lds<<<MPAD / 64, 256, 0, stream>>>(a_bf, w2t, h_bf);
    agg2_mm3_kernel<<<(NNODES + 3) / 4, 256, 0, stream>>>((const ushort4*)h_bf, h3,
                                                          dinv, rp, csr, wcsr, b2, W3, NNODES);
    final_kernel<<<(NNODES + 255) / 256, 256, 0, stream>>>(h3, dinv, rp, csr, wcsr, b3, out, NNODES);
}